// Round 1
// baseline (904.405 us; speedup 1.0000x reference)
//
#include <hip/hip_runtime.h>
#include <stdint.h>
#include <stddef.h>

#define M_SZ 8192
#define F_DIM 512
#define N_Q 32768

typedef __attribute__((ext_vector_type(4))) float f32x4;
typedef __attribute__((ext_vector_type(8))) __bf16 bf16x8;

__device__ __forceinline__ unsigned bfround_bits(float x) {
    union { float f; unsigned u; } v; v.f = x;
    return (v.u + 0x7fffu + ((v.u >> 16) & 1u)) & 0xffff0000u;
}
__device__ __forceinline__ float bits_to_f(unsigned u) {
    union { unsigned u; float f; } v; v.u = u; return v.f;
}
__device__ __forceinline__ unsigned short f2bf(float x) {
    return (unsigned short)(bfround_bits(x) >> 16);
}

// ---------------------------------------------------------------------------
// Kernel 1: row-normalize positions & embeddings; pad to float4 for staging.
// ---------------------------------------------------------------------------
__global__ void prep_kernel(const float* __restrict__ pos,
                            const float* __restrict__ emb,
                            float* __restrict__ pn4,
                            float* __restrict__ en4,
                            float* __restrict__ pos4) {
    int i = blockIdx.x * 256 + threadIdx.x;
    if (i >= M_SZ) return;
    float x = pos[i * 3 + 0], y = pos[i * 3 + 1], z = pos[i * 3 + 2];
    float inv = 1.0f / __builtin_amdgcn_sqrtf(x * x + y * y + z * z);
    pn4[i * 4 + 0] = x * inv; pn4[i * 4 + 1] = y * inv;
    pn4[i * 4 + 2] = z * inv; pn4[i * 4 + 3] = 0.0f;
    pos4[i * 4 + 0] = x; pos4[i * 4 + 1] = y;
    pos4[i * 4 + 2] = z; pos4[i * 4 + 3] = 0.0f;
    float ex = emb[i * 3 + 0], ey = emb[i * 3 + 1], ez = emb[i * 3 + 2];
    float einv = 1.0f / __builtin_amdgcn_sqrtf(ex * ex + ey * ey + ez * ez);
    en4[i * 4 + 0] = ex * einv; en4[i * 4 + 1] = ey * einv;
    en4[i * 4 + 2] = ez * einv; en4[i * 4 + 3] = 0.0f;
}

// ---------------------------------------------------------------------------
// Kernel 2: features [8192,512] fp32 -> featT [512,8192] bf16 (K-contiguous
// for MFMA B-fragments). 64x64 tiles via LDS.
// ---------------------------------------------------------------------------
__global__ void transpose_kernel(const float* __restrict__ feat,
                                 unsigned short* __restrict__ featT) {
    __shared__ float tile[64 * 65];
    const int jb = blockIdx.x * 64, fb = blockIdx.y * 64;
    const int t = threadIdx.x;
#pragma unroll
    for (int p = 0; p < 16; ++p) {
        int idx = p * 256 + t;
        int j = idx >> 6, f = idx & 63;
        tile[j * 65 + f] = feat[(size_t)(jb + j) * F_DIM + fb + f];
    }
    __syncthreads();
#pragma unroll
    for (int p = 0; p < 16; ++p) {
        int idx = p * 256 + t;
        int f = idx >> 6, j = idx & 63;
        featT[(size_t)(fb + f) * M_SZ + jb + j] = f2bf(tile[j * 65 + f]);
    }
}

// ---------------------------------------------------------------------------
// Kernel 3: fused softmax(pn@en^T) @ [features | positions].
// Produces memT [512,8192] bf16 (pre-normalized) and npe4 [8192,4] fp32
// (x,y,z,|npe|^2). Tile BM=64 (m rows), BN=256 (f cols, 2 blocks), BK=32.
// ---------------------------------------------------------------------------
__launch_bounds__(256, 3)
__global__ void build_memory_kernel(const float* __restrict__ pn4,
                                    const float* __restrict__ en4,
                                    const float* __restrict__ pos4,
                                    const unsigned short* __restrict__ featT,
                                    unsigned short* __restrict__ memT,
                                    float* __restrict__ npe4) {
    constexpr int BM = 64, BN = 256, BK = 32;
    constexpr int PSTR = BK + 8;  // 40 bf16 = 80 B: 16B-bank map r*5%8, conflict-free
    __shared__ unsigned short pbuf[BM * PSTR];
    __shared__ unsigned short vbuf[BN * PSTR];
    __shared__ f32x4 etile[BK];
    __shared__ f32x4 ptile[BK];
    __shared__ f32x4 red[256];
    __shared__ float lbuf[BM];

    const int t = threadIdx.x;
    const int lane = t & 63, wv = t >> 6;
    const int mb = blockIdx.x * BM, fb = blockIdx.y * BN;
    const int r = t & 63, jq = t >> 6;  // P-row, j-chunk (8 j's each)

    const f32x4 pnr = ((const f32x4*)pn4)[mb + r];

    f32x4 acc[4][4];
    const f32x4 zero4 = {0.f, 0.f, 0.f, 0.f};
#pragma unroll
    for (int m = 0; m < 4; ++m)
#pragma unroll
        for (int n = 0; n < 4; ++n) acc[m][n] = zero4;
    float nx = 0.f, ny = 0.f, nz = 0.f, lp = 0.f;

    const unsigned short* vsrc = featT + (size_t)(fb + t) * M_SZ;

    for (int kt = 0; kt < M_SZ / BK; ++kt) {
        const int jb2 = kt * BK;
        __syncthreads();  // previous iter's MFMA reads done
        if (t < BK) etile[t] = ((const f32x4*)en4)[jb2 + t];
        else if (t < 2 * BK) ptile[t - BK] = ((const f32x4*)pos4)[jb2 + t - BK];
        const uint4* g = (const uint4*)(vsrc + jb2);
        uint4 v0 = g[0], v1 = g[1], v2 = g[2], v3 = g[3];
        __syncthreads();  // etile/ptile visible

        // P = exp(pn . en[j]), bf16-rounded; accumulate l and npe from the
        // SAME rounded values for numerator/denominator consistency.
        unsigned pk[4];
#pragma unroll
        for (int i = 0; i < 8; i += 2) {
            int j = jq * 8 + i;
            f32x4 e0 = etile[j], e1 = etile[j + 1];
            float s0 = fmaf(pnr.x, e0.x, fmaf(pnr.y, e0.y, pnr.z * e0.z));
            float s1 = fmaf(pnr.x, e1.x, fmaf(pnr.y, e1.y, pnr.z * e1.z));
            unsigned b0 = bfround_bits(__builtin_amdgcn_exp2f(s0 * 1.44269504f));
            unsigned b1 = bfround_bits(__builtin_amdgcn_exp2f(s1 * 1.44269504f));
            float w0 = bits_to_f(b0), w1 = bits_to_f(b1);
            f32x4 p0 = ptile[j], p1 = ptile[j + 1];
            lp += w0 + w1;
            nx = fmaf(w0, p0.x, fmaf(w1, p1.x, nx));
            ny = fmaf(w0, p0.y, fmaf(w1, p1.y, ny));
            nz = fmaf(w0, p0.z, fmaf(w1, p1.z, nz));
            pk[i >> 1] = (b0 >> 16) | (b1 & 0xffff0000u);
        }
        *(uint4*)(pbuf + r * PSTR + jq * 8) = make_uint4(pk[0], pk[1], pk[2], pk[3]);
        uint4* vd = (uint4*)(vbuf + t * PSTR);
        vd[0] = v0; vd[1] = v1; vd[2] = v2; vd[3] = v3;
        __syncthreads();  // pbuf/vbuf visible

        const int col = lane & 15, quad = lane >> 4;
        bf16x8 a[4];
#pragma unroll
        for (int m = 0; m < 4; ++m)
            a[m] = *(const bf16x8*)(pbuf + (m * 16 + col) * PSTR + quad * 8);
#pragma unroll
        for (int n = 0; n < 4; ++n) {
            bf16x8 b = *(const bf16x8*)(vbuf + ((wv * 4 + n) * 16 + col) * PSTR + quad * 8);
#pragma unroll
            for (int m = 0; m < 4; ++m)
                acc[m][n] = __builtin_amdgcn_mfma_f32_16x16x32_bf16(a[m], b, acc[m][n], 0, 0, 0);
        }
    }

    // combine per-row partials (4 threads per row)
    f32x4 mine = {nx, ny, nz, lp};
    red[t] = mine;
    __syncthreads();
    if (t < BM) {
        f32x4 s = red[t];
        f32x4 s1 = red[t + 64], s2 = red[t + 128], s3 = red[t + 192];
        s.x += s1.x + s2.x + s3.x;
        s.y += s1.y + s2.y + s3.y;
        s.z += s1.z + s2.z + s3.z;
        s.w += s1.w + s2.w + s3.w;
        lbuf[t] = s.w;
        if (blockIdx.y == 0) {
            float inv = 1.0f / s.w;
            float X = s.x * inv, Y = s.y * inv, Z = s.z * inv;
            f32x4 o = {X, Y, Z, X * X + Y * Y + Z * Z};
            ((f32x4*)npe4)[mb + t] = o;
        }
    }
    __syncthreads();

    // store memT[f][m] = acc/l in bf16 (C layout: col=lane&15, row=quad*4+reg)
    const int col = lane & 15, quad = lane >> 4;
#pragma unroll
    for (int m = 0; m < 4; ++m) {
        f32x4 l4 = *(const f32x4*)(lbuf + m * 16 + quad * 4);
        f32x4 inv4 = {1.0f / l4.x, 1.0f / l4.y, 1.0f / l4.z, 1.0f / l4.w};
        int mg = mb + m * 16 + quad * 4;
#pragma unroll
        for (int n = 0; n < 4; ++n) {
            int fg = fb + (wv * 4 + n) * 16 + col;
            ushort4 o;
            o.x = f2bf(acc[m][n].x * inv4.x);
            o.y = f2bf(acc[m][n].y * inv4.y);
            o.z = f2bf(acc[m][n].z * inv4.z);
            o.w = f2bf(acc[m][n].w * inv4.w);
            *(ushort4*)(memT + (size_t)fg * M_SZ + mg) = o;
        }
    }
}

// ---------------------------------------------------------------------------
// Kernel 4: fused softmax(-cdist(q, npe)) @ memory.
// Tile BM=128 (queries), BN=256 (f cols, 2 blocks), BK=32.
// ---------------------------------------------------------------------------
__launch_bounds__(256, 2)
__global__ void query_kernel(const float* __restrict__ qpos,
                             const float* __restrict__ npe4,
                             const unsigned short* __restrict__ memT,
                             float* __restrict__ out) {
    constexpr int BM = 128, BN = 256, BK = 32;
    constexpr int PSTR = BK + 8;  // 40
    __shared__ unsigned short pbuf[BM * PSTR];
    __shared__ unsigned short vbuf[BN * PSTR];
    __shared__ f32x4 ntile[BK];
    __shared__ float red[256];
    __shared__ float lbuf[BM];

    const int t = threadIdx.x;
    const int lane = t & 63, wv = t >> 6;
    const int qb = blockIdx.x * BM, fb = blockIdx.y * BN;
    const int r = t & 127, jh = t >> 7;  // P-row, j-half (16 j's each)

    const float qx = qpos[(size_t)(qb + r) * 3 + 0];
    const float qy = qpos[(size_t)(qb + r) * 3 + 1];
    const float qz = qpos[(size_t)(qb + r) * 3 + 2];
    const float q2 = qx * qx + qy * qy + qz * qz;

    f32x4 acc[8][4];
    const f32x4 zero4 = {0.f, 0.f, 0.f, 0.f};
#pragma unroll
    for (int m = 0; m < 8; ++m)
#pragma unroll
        for (int n = 0; n < 4; ++n) acc[m][n] = zero4;
    float lp = 0.f;

    const unsigned short* vsrc = memT + (size_t)(fb + t) * M_SZ;

    for (int kt = 0; kt < M_SZ / BK; ++kt) {
        const int jb2 = kt * BK;
        __syncthreads();
        if (t < BK) ntile[t] = ((const f32x4*)npe4)[jb2 + t];
        const uint4* g = (const uint4*)(vsrc + jb2);
        uint4 v0 = g[0], v1 = g[1], v2 = g[2], v3 = g[3];
        __syncthreads();

        // P = exp(-sqrt(max(q2 + n2 - 2 q.n, eps)))  -- matches ref cdist
        unsigned pk[8];
#pragma unroll
        for (int i = 0; i < 16; i += 2) {
            int j = jh * 16 + i;
            f32x4 n0 = ntile[j], n1 = ntile[j + 1];
            float d0 = fmaf(qx, n0.x, fmaf(qy, n0.y, qz * n0.z));
            float d1 = fmaf(qx, n1.x, fmaf(qy, n1.y, qz * n1.z));
            float t0 = fmaf(-2.0f, d0, q2 + n0.w);
            float t1 = fmaf(-2.0f, d1, q2 + n1.w);
            t0 = fmaxf(t0, 1e-12f);
            t1 = fmaxf(t1, 1e-12f);
            float dd0 = __builtin_amdgcn_sqrtf(t0);
            float dd1 = __builtin_amdgcn_sqrtf(t1);
            unsigned b0 = bfround_bits(__builtin_amdgcn_exp2f(dd0 * -1.44269504f));
            unsigned b1 = bfround_bits(__builtin_amdgcn_exp2f(dd1 * -1.44269504f));
            lp += bits_to_f(b0) + bits_to_f(b1);
            pk[i >> 1] = (b0 >> 16) | (b1 & 0xffff0000u);
        }
        uint4* pd = (uint4*)(pbuf + r * PSTR + jh * 16);
        pd[0] = make_uint4(pk[0], pk[1], pk[2], pk[3]);
        pd[1] = make_uint4(pk[4], pk[5], pk[6], pk[7]);
        uint4* vd = (uint4*)(vbuf + t * PSTR);
        vd[0] = v0; vd[1] = v1; vd[2] = v2; vd[3] = v3;
        __syncthreads();

        const int col = lane & 15, quad = lane >> 4;
        bf16x8 a[8];
#pragma unroll
        for (int m = 0; m < 8; ++m)
            a[m] = *(const bf16x8*)(pbuf + (m * 16 + col) * PSTR + quad * 8);
#pragma unroll
        for (int n = 0; n < 4; ++n) {
            bf16x8 b = *(const bf16x8*)(vbuf + ((wv * 4 + n) * 16 + col) * PSTR + quad * 8);
#pragma unroll
            for (int m = 0; m < 8; ++m)
                acc[m][n] = __builtin_amdgcn_mfma_f32_16x16x32_bf16(a[m], b, acc[m][n], 0, 0, 0);
        }
    }

    red[t] = lp;
    __syncthreads();
    if (t < BM) lbuf[t] = red[t] + red[t + 128];
    __syncthreads();

    const int col = lane & 15, quad = lane >> 4;
#pragma unroll
    for (int m = 0; m < 8; ++m) {
        f32x4 l4 = *(const f32x4*)(lbuf + m * 16 + quad * 4);
        f32x4 inv4 = {1.0f / l4.x, 1.0f / l4.y, 1.0f / l4.z, 1.0f / l4.w};
        int qg = qb + m * 16 + quad * 4;
#pragma unroll
        for (int n = 0; n < 4; ++n) {
            int fg = fb + (wv * 4 + n) * 16 + col;
            out[(size_t)(qg + 0) * F_DIM + fg] = acc[m][n].x * inv4.x;
            out[(size_t)(qg + 1) * F_DIM + fg] = acc[m][n].y * inv4.y;
            out[(size_t)(qg + 2) * F_DIM + fg] = acc[m][n].z * inv4.z;
            out[(size_t)(qg + 3) * F_DIM + fg] = acc[m][n].w * inv4.w;
        }
    }
}

// ---------------------------------------------------------------------------
// Workspace layout (bytes):
//   featT : [0,        8388608)   512x8192 bf16
//   memT  : [8388608, 16777216)   512x8192 bf16
//   npe4  : [16777216,16908288)   8192x4 fp32 (x,y,z,|npe|^2)
//   pn4   : [16908288,17039360)
//   en4   : [17039360,17170432)
//   pos4  : [17170432,17301504)
// ---------------------------------------------------------------------------
extern "C" void kernel_launch(void* const* d_in, const int* in_sizes, int n_in,
                              void* d_out, int out_size, void* d_ws, size_t ws_size,
                              hipStream_t stream) {
    const float* features  = (const float*)d_in[0];
    const float* positions = (const float*)d_in[1];
    const float* qpos      = (const float*)d_in[2];
    const float* pemb      = (const float*)d_in[3];
    float* out = (float*)d_out;
    char* ws = (char*)d_ws;

    unsigned short* featT = (unsigned short*)(ws);
    unsigned short* memT  = (unsigned short*)(ws + 8388608);
    float* npe4 = (float*)(ws + 16777216);
    float* pn4  = (float*)(ws + 16908288);
    float* en4  = (float*)(ws + 17039360);
    float* pos4 = (float*)(ws + 17170432);

    hipLaunchKernelGGL(prep_kernel, dim3(M_SZ / 256), dim3(256), 0, stream,
                       positions, pemb, pn4, en4, pos4);
    hipLaunchKernelGGL(transpose_kernel, dim3(M_SZ / 64, F_DIM / 64), dim3(256), 0, stream,
                       features, featT);
    hipLaunchKernelGGL(build_memory_kernel, dim3(M_SZ / 64, F_DIM / 256), dim3(256), 0, stream,
                       pn4, en4, pos4, featT, memT, npe4);
    hipLaunchKernelGGL(query_kernel, dim3(N_Q / 128, F_DIM / 256), dim3(256), 0, stream,
                       qpos, npe4, memT, out);
}